// Round 5
// baseline (725.168 us; speedup 1.0000x reference)
//
#include <hip/hip_runtime.h>
#include <cstdint>

// ---------------------------------------------------------------------------
// PureCorrelation: out = (mask' . relu(Q @ Kp^T)) @ Vp
//   Kp = K W1^T + b1,  Vp = V W2^T + b2,  mask' = mask with col0 true.
// R11: revert to split GEMMs (R4 fused was LDS-BW-bound: each QK B-frag read
// fed 1 MFMA). Fixes vs R8:
//   1) alpha256p: 256x256 8-phase GEMM made PERSISTENT over bz (grid=256,
//      each block does bz=0..3 with full pipeline flush + re-prime per batch;
//      ledger stays clean: stores drain under the next prologue's vmcnt(4)).
//      Kills the 4 launch-round fill/drain penalties of R8's grid=1024.
//   2) outg: 8-phase at BM=128 x BN=256 (was 256x128). A=alpha re-fetch drops
//      from 4x to 2x (~600 -> ~335 MB): the R8 out-GEMM was HBM-bound.
//      Per-wave 64x64, LDS 96 KiB, same counted-vmcnt(4) ledger (A=2,B=4
//      stage-calls per K-tile).
// 4 graph nodes: prep -> proj -> alpha256p -> outg.
// ---------------------------------------------------------------------------

typedef __bf16 bf16x8 __attribute__((ext_vector_type(8)));
typedef float f32x4 __attribute__((ext_vector_type(4)));

__device__ __forceinline__ unsigned short f2bf(float f) {
  unsigned int u = __float_as_uint(f);
  u += 0x7fffu + ((u >> 16) & 1u);
  return (unsigned short)(u >> 16);
}

// async global->LDS, 16B per lane. LDS dest is wave-uniform base + lane*16.
__device__ __forceinline__ void async_load16(const void* g, void* l) {
  __builtin_amdgcn_global_load_lds(
      (const __attribute__((address_space(1))) unsigned int*)(uintptr_t)g,
      (__attribute__((address_space(3))) unsigned int*)(unsigned int)(uintptr_t)l,
      16, 0, 0);
}

// ---------------------------------------------------------------------------
// prep: blocks [0,24576) cvt Q/K/V; [24576,25088) cvt W1/W2; rest pack mask.
// ---------------------------------------------------------------------------
__global__ void __launch_bounds__(256)
prep(const float* __restrict__ q, const float* __restrict__ k,
     const float* __restrict__ v, const float* __restrict__ w1,
     const float* __restrict__ w2, const int* __restrict__ m,
     unsigned short* __restrict__ qb, unsigned short* __restrict__ kb,
     unsigned short* __restrict__ vb, unsigned short* __restrict__ w1b,
     unsigned short* __restrict__ w2b, unsigned int* __restrict__ bits) {
  const int b = blockIdx.x, tid = threadIdx.x;
  if (b < 24576) {                       // Q/K/V fp32->bf16, 8192 blocks each
    const int which = b >> 13;
    const int idx = (b & 8191) * 256 + tid;
    const float* in = (which == 0) ? q : (which == 1) ? k : v;
    unsigned short* out = (which == 0) ? qb : (which == 1) ? kb : vb;
    float4 f = ((const float4*)in)[idx];
    ushort4 o;
    o.x = f2bf(f.x); o.y = f2bf(f.y); o.z = f2bf(f.z); o.w = f2bf(f.w);
    ((ushort4*)out)[idx] = o;
  } else if (b < 25088) {                // W1/W2 fp32->bf16, 256 blocks each
    const int which = (b - 24576) >> 8;
    const int idx = ((b - 24576) & 255) * 256 + tid;
    const float* in = (which == 0) ? w1 : w2;
    unsigned short* out = (which == 0) ? w1b : w2b;
    float4 f = ((const float4*)in)[idx];
    ushort4 o;
    o.x = f2bf(f.x); o.y = f2bf(f.y); o.z = f2bf(f.z); o.w = f2bf(f.w);
    ((ushort4*)out)[idx] = o;
  } else {                               // mask -> bits (col 0 forced true)
    const int lane = tid & 63;
    const size_t wid = (size_t)(b - 25088) * 4 + (tid >> 6);
    const size_t base = wid * 256;
    unsigned long long bl[4];
#pragma unroll
    for (int c = 0; c < 4; ++c) {
      size_t e = base + (size_t)c * 64 + lane;
      int col = (int)(e & 4095);  // S = 4096
      bl[c] = __ballot((m[e] != 0) || (col == 0));
    }
    if (lane < 8)
      bits[base / 32 + lane] = (unsigned int)(bl[lane >> 1] >> ((lane & 1) * 32));
  }
}

// ---------------------------------------------------------------------------
// proj: both E-projections in one launch. Blocks [0,512): Kp = Kb@W1^T+b1
// (M=16384,N=512). Blocks [512,1024): Vpt[b][f][s] = W2@Vb^T+b2 (M=512,N=4096,
// per batch). K=512, lda=ldb=512, BK=64 m97-pattern staging.
// ---------------------------------------------------------------------------
__global__ void __launch_bounds__(256)
proj(const unsigned short* __restrict__ Kb, const unsigned short* __restrict__ W1b,
     unsigned short* __restrict__ Kp, const float* __restrict__ b1,
     const unsigned short* __restrict__ W2b, const unsigned short* __restrict__ Vb,
     unsigned short* __restrict__ Vpt, const float* __restrict__ b2) {
  constexpr int K = 512;
  constexpr long long SE = 4096LL * 512;
  __shared__ unsigned short sA[2 * 128 * 32];
  __shared__ unsigned short sB[2 * 128 * 32];

  const int L = blockIdx.x;
  const unsigned short *Ab, *Bb;
  unsigned short* C;
  const float* bias;
  int tm0, tn0, N, epi;
  if (L < 512) {                 // Kp projection
    tn0 = (L & 3) * 128; tm0 = (L >> 2) * 128;
    Ab = Kb; Bb = W1b; C = Kp; bias = b1; N = 512; epi = 0;
  } else {                       // Vpt projection
    const int t = L - 512;
    tn0 = (t & 31) * 128; tm0 = ((t >> 5) & 3) * 128;
    const int bz = t >> 7;
    Ab = W2b; Bb = Vb + (size_t)bz * SE; C = Vpt + (size_t)bz * SE;
    bias = b2; N = 4096; epi = 1;
  }

  const int tid = threadIdx.x;
  const int lane = tid & 63, wave = tid >> 6;
  const int ldrow = lane >> 2, lcol = (lane & 3) * 8;
  const int wm = (wave >> 1) * 64, wn = (wave & 1) * 64;
  const int lr = lane & 15, lq = lane >> 4;

  f32x4 acc[4][4] = {};

  for (int k0 = 0; k0 < K; k0 += 64) {
#pragma unroll
    for (int g = 0; g < 2; ++g)
#pragma unroll
      for (int l = 0; l < 2; ++l) {
        const int row = wave * 32 + l * 16;
        async_load16(Ab + (size_t)(tm0 + row + ldrow) * K + (k0 + g * 32 + lcol),
                     &sA[g * 4096 + row * 32]);
        async_load16(Bb + (size_t)(tn0 + row + ldrow) * K + (k0 + g * 32 + lcol),
                     &sB[g * 4096 + row * 32]);
      }
    __syncthreads();
#pragma unroll
    for (int g = 0; g < 2; ++g) {
      bf16x8 af[4], bfr[4];
#pragma unroll
      for (int t = 0; t < 4; ++t) {
        af[t]  = *(const bf16x8*)&sA[g * 4096 + (wm + t * 16 + lr) * 32 + lq * 8];
        bfr[t] = *(const bf16x8*)&sB[g * 4096 + (wn + t * 16 + lr) * 32 + lq * 8];
      }
#pragma unroll
      for (int mt = 0; mt < 4; ++mt)
#pragma unroll
        for (int nt = 0; nt < 4; ++nt)
          acc[mt][nt] = __builtin_amdgcn_mfma_f32_16x16x32_bf16(af[mt], bfr[nt],
                                                                acc[mt][nt], 0, 0, 0);
    }
    __syncthreads();
  }

#pragma unroll
  for (int mt = 0; mt < 4; ++mt)
#pragma unroll
    for (int r = 0; r < 4; ++r) {
      const int mm = tm0 + wm + mt * 16 + lq * 4 + r;
#pragma unroll
      for (int nt = 0; nt < 4; ++nt) {
        const int n = tn0 + wn + nt * 16 + lr;
        float v = acc[mt][nt][r];
        v += (epi == 0) ? bias[n] : bias[mm];
        C[(size_t)mm * N + n] = f2bf(v);
      }
    }
}

// ---------------------------------------------------------------------------
// alpha256p: 256x256-tile 8-phase GEMM, persistent over batches (grid=256).
// Full flush + re-prime per bz; clean counted-vmcnt ledger.
// ---------------------------------------------------------------------------
__global__ void __launch_bounds__(512, 2)
alpha256p(const unsigned short* __restrict__ A, const unsigned short* __restrict__ B,
          unsigned short* __restrict__ Cw, const unsigned int* __restrict__ mbits,
          int M, int N, int K,
          long long strA, long long strB, long long strC, long long strM) {
  __shared__ unsigned short sA[2][256][64];
  __shared__ unsigned short sB[2][256][64];

  int lin = blockIdx.x;
  lin = (lin & 7) * 32 + (lin >> 3);
  const int bx = lin & 15;
  const int by = lin >> 4;
  const int tn0 = bx << 8, tm0 = by << 8;

  const int tid  = threadIdx.x;
  const int lane = tid & 63;
  const int w    = tid >> 6;
  const int wr   = w >> 2;
  const int wc   = w & 3;
  const int lr   = lane & 15;
  const int lq   = lane >> 4;

  const int srow = tid >> 3;
  const int scol = (((tid & 7) ^ (srow & 7)) << 3);
  const int sdst = tid << 4;

#define STAGE64(bufbase, g, t0, k0, R0)                                      \
  async_load16((g) + (size_t)((t0) + (R0) + srow) * K + (k0) + scol,         \
               (char*)(bufbase) + ((R0) << 7) + sdst)

  const int sxor  = (lr & 7) << 4;
  const int k0off = (lq << 4) ^ sxor;
  const int k1off = (64 | (lq << 4)) ^ sxor;
  const int aRow  = (wr * 128 + lr) * 128;
  const int bRow  = (wc * 64 + lr) * 128;

#define LDA(d, mh, mt2, kk)                                                  \
  (*(const bf16x8*)((const char*)sA[d] + aRow + (mh) * 8192 + (mt2) * 2048 + \
                    k##kk##off))
#define LDB(d, nh, nt2, kk)                                                  \
  (*(const bf16x8*)((const char*)sB[d] + bRow + (nh) * 4096 + (nt2) * 2048 + \
                    k##kk##off))

  bf16x8 afr[4][2];
  bf16x8 bfr[4][2];

#define RDA(d, mh)                                                           \
  _Pragma("unroll") for (int mt2 = 0; mt2 < 4; ++mt2) {                      \
    afr[mt2][0] = LDA(d, mh, mt2, 0);                                        \
    afr[mt2][1] = LDA(d, mh, mt2, 1);                                        \
  }
#define RDB(d, nh)                                                           \
  _Pragma("unroll") for (int nt2 = 0; nt2 < 2; ++nt2) {                      \
    bfr[(nh) * 2 + nt2][0] = LDB(d, nh, nt2, 0);                             \
    bfr[(nh) * 2 + nt2][1] = LDB(d, nh, nt2, 1);                             \
  }
#define MFMAQ(mh, nh)                                                        \
  __builtin_amdgcn_s_setprio(1);                                             \
  _Pragma("unroll") for (int mt2 = 0; mt2 < 4; ++mt2)                        \
  _Pragma("unroll") for (int nt2 = 0; nt2 < 2; ++nt2) {                      \
    acc[(mh) * 4 + mt2][(nh) * 2 + nt2] =                                    \
        __builtin_amdgcn_mfma_f32_16x16x32_bf16(                             \
            afr[mt2][0], bfr[(nh) * 2 + nt2][0],                             \
            acc[(mh) * 4 + mt2][(nh) * 2 + nt2], 0, 0, 0);                   \
    acc[(mh) * 4 + mt2][(nh) * 2 + nt2] =                                    \
        __builtin_amdgcn_mfma_f32_16x16x32_bf16(                             \
            afr[mt2][1], bfr[(nh) * 2 + nt2][1],                             \
            acc[(mh) * 4 + mt2][(nh) * 2 + nt2], 0, 0, 0);                   \
  }                                                                          \
  __builtin_amdgcn_s_setprio(0);
#define BAR __builtin_amdgcn_s_barrier()

  const int nIter = K >> 7;   // 4

  for (int vz = 0; vz < 4; ++vz) {
    const unsigned short* Ab = A + (size_t)vz * strA;
    const unsigned short* Bb = B + (size_t)vz * strB;

    f32x4 acc[8][4] = {};

    STAGE64(sB[0], Bb, tn0, 0, 0);   STAGE64(sB[0], Bb, tn0, 0, 64);
    STAGE64(sB[0], Bb, tn0, 0, 128); STAGE64(sB[0], Bb, tn0, 0, 192);
    STAGE64(sA[0], Ab, tm0, 0, 0);   STAGE64(sA[0], Ab, tm0, 0, 64);
    STAGE64(sA[0], Ab, tm0, 0, 128); STAGE64(sA[0], Ab, tm0, 0, 192);
    STAGE64(sB[1], Bb, tn0, 64, 0);  STAGE64(sB[1], Bb, tn0, 64, 64);
    STAGE64(sB[1], Bb, tn0, 64, 128);STAGE64(sB[1], Bb, tn0, 64, 192);
    asm volatile("s_waitcnt vmcnt(4)" ::: "memory");
    BAR;

    for (int j = 0; j < nIter; ++j) {
      const int kb = j << 7;
      const bool pf = (j + 1 < nIter);
      RDA(0, 0); RDB(0, 0);
      STAGE64(sA[1], Ab, tm0, kb + 64, 0);
      STAGE64(sA[1], Ab, tm0, kb + 64, 64);
      BAR; MFMAQ(0, 0); BAR;
      RDB(0, 1);
      STAGE64(sA[1], Ab, tm0, kb + 64, 128);
      STAGE64(sA[1], Ab, tm0, kb + 64, 192);
      BAR; MFMAQ(0, 1); BAR;
      RDA(0, 1);
      if (pf) { STAGE64(sB[0], Bb, tn0, kb + 128, 0);
                STAGE64(sB[0], Bb, tn0, kb + 128, 64); }
      BAR; MFMAQ(1, 1); BAR;
      if (pf) { STAGE64(sB[0], Bb, tn0, kb + 128, 128);
                STAGE64(sB[0], Bb, tn0, kb + 128, 192); }
      BAR; MFMAQ(1, 0);
      if (pf) asm volatile("s_waitcnt vmcnt(4)" ::: "memory");
      else    asm volatile("s_waitcnt vmcnt(0)" ::: "memory");
      BAR;
      RDA(1, 0); RDB(1, 0);
      if (pf) { STAGE64(sA[0], Ab, tm0, kb + 128, 0);
                STAGE64(sA[0], Ab, tm0, kb + 128, 64); }
      BAR; MFMAQ(0, 0); BAR;
      RDB(1, 1);
      if (pf) { STAGE64(sA[0], Ab, tm0, kb + 128, 128);
                STAGE64(sA[0], Ab, tm0, kb + 128, 192); }
      BAR; MFMAQ(0, 1); BAR;
      RDA(1, 1);
      if (pf) { STAGE64(sB[1], Bb, tn0, kb + 192, 0);
                STAGE64(sB[1], Bb, tn0, kb + 192, 64); }
      BAR; MFMAQ(1, 1); BAR;
      if (pf) { STAGE64(sB[1], Bb, tn0, kb + 192, 128);
                STAGE64(sB[1], Bb, tn0, kb + 192, 192); }
      BAR; MFMAQ(1, 0);
      asm volatile("s_waitcnt vmcnt(4)" ::: "memory");
      BAR;
    }

#pragma unroll
    for (int mt = 0; mt < 8; ++mt) {
#pragma unroll
      for (int r = 0; r < 4; ++r) {
        const int m = tm0 + wr * 128 + mt * 16 + lq * 4 + r;
        unsigned long long w64 =
            *(const unsigned long long*)&mbits[(size_t)vz * strM +
                                               (size_t)m * (N >> 5) +
                                               ((tn0 + wc * 64) >> 5)];
#pragma unroll
        for (int nt = 0; nt < 4; ++nt) {
          const int n = tn0 + wc * 64 + nt * 16 + lr;
          float v = acc[mt][nt][r];
          v = ((w64 >> (nt * 16 + lr)) & 1ull) ? fmaxf(v, 0.f) : 0.f;
          Cw[(size_t)vz * strC + (size_t)m * N + n] = f2bf(v);
        }
      }
    }
  }
#undef STAGE64
#undef LDA
#undef LDB
#undef RDA
#undef RDB
#undef MFMAQ
#undef BAR
}

// ---------------------------------------------------------------------------
// outg: 8-phase GEMM at BM=128 x BN=256, C = A[M,K] @ B[N,K]^T, fp32 out.
// Per-wave 64x64 (acc[4][4]); A=2, B=4 stage-calls/K-tile; vmcnt(4) gates.
// ---------------------------------------------------------------------------
__global__ void __launch_bounds__(512, 2)
outg(const unsigned short* __restrict__ A, const unsigned short* __restrict__ B,
     float* __restrict__ Cout, int M, int N, int K,
     long long strA, long long strB, long long strC) {
  __shared__ unsigned short sA[2][128][64];
  __shared__ unsigned short sB[2][256][64];

  int lin = blockIdx.x;
  lin = (lin & 7) * ((int)gridDim.x >> 3) + (lin >> 3);
  const int tilesN = N >> 8;    // 2
  const int tilesM = M >> 7;    // 32
  const int bx = lin % tilesN;
  const int by = (lin / tilesN) % tilesM;
  const int bz = lin / (tilesN * tilesM);

  const int tn0 = bx << 8, tm0 = by << 7;
  const unsigned short* Ab = A + (size_t)bz * strA;
  const unsigned short* Bb = B + (size_t)bz * strB;

  const int tid  = threadIdx.x;
  const int lane = tid & 63;
  const int w    = tid >> 6;
  const int wr   = w >> 2;
  const int wc   = w & 3;
  const int lr   = lane & 15;
  const int lq   = lane >> 4;

  const int srow = tid >> 3;
  const int scol = (((tid & 7) ^ (srow & 7)) << 3);
  const int sdst = tid << 4;

#define OST(bufbase, g, t0, k0, R0)                                          \
  async_load16((g) + (size_t)((t0) + (R0) + srow) * K + (k0) + scol,         \
               (char*)(bufbase) + ((R0) << 7) + sdst)

  const int sxor  = (lr & 7) << 4;
  const int k0off = (lq << 4) ^ sxor;
  const int k1off = (64 | (lq << 4)) ^ sxor;
  const int aRow  = (wr * 64 + lr) * 128;
  const int bRow  = (wc * 64 + lr) * 128;

#define OLDA(d, mh, mt2, kk)                                                 \
  (*(const bf16x8*)((const char*)sA[d] + aRow + (mh) * 4096 + (mt2) * 2048 + \
                    k##kk##off))
#define OLDB(d, nh, nt2, kk)                                                 \
  (*(const bf16x8*)((const char*)sB[d] + bRow + (nh) * 4096 + (nt2) * 2048 + \
                    k##kk##off))

  f32x4 acc[4][4] = {};
  bf16x8 afr[2][2];
  bf16x8 bfr[4][2];

#define ORDA(d, mh)                                                          \
  _Pragma("unroll") for (int mt2 = 0; mt2 < 2; ++mt2) {                      \
    afr[mt2][0] = OLDA(d, mh, mt2, 0);                                       \
    afr[mt2][1] = OLDA(d, mh, mt2, 1);                                       \
  }
#define ORDB(d, nh)                                                          \
  _Pragma("unroll") for (int nt2 = 0; nt2 < 2; ++nt2) {                      \
    bfr[(nh) * 2 + nt2][0] = OLDB(d, nh, nt2, 0);                            \
    bfr[(nh) * 2 + nt2][1] = OLDB(d, nh, nt2, 1);                            \
  }
#define OMFMAQ(mh, nh)                                                       \
  __builtin_amdgcn_s_setprio(1);                                             \
  _Pragma("unroll") for (int mt2 = 0; mt2 < 2; ++mt2)                        \
  _Pragma("unroll") for (int nt2 = 0; nt2 < 2; ++nt2) {                      \
    acc[(mh) * 2 + mt2][(nh) * 2 + nt2] =                                    \
        __builtin_amdgcn_mfma_f32_16x16x32_bf16(                             \
            afr[mt2][0], bfr[(nh) * 2 + nt2][0],                             \
            acc[(mh) * 2 + mt2][(nh) * 2 + nt2], 0, 0, 0);                   \
    acc[(mh) * 2 + mt2][(nh) * 2 + nt2] =                                    \
        __builtin_amdgcn_mfma_f32_16x16x32_bf16(                             \
            afr[mt2][1], bfr[(nh) * 2 + nt2][1],                             \
            acc[(mh) * 2 + mt2][(nh) * 2 + nt2], 0, 0, 0);                   \
  }                                                                          \
  __builtin_amdgcn_s_setprio(0);
#define OBAR __builtin_amdgcn_s_barrier()

  const int nIter = K >> 7;   // 32

  OST(sB[0], Bb, tn0, 0, 0);   OST(sB[0], Bb, tn0, 0, 64);
  OST(sB[0], Bb, tn0, 0, 128); OST(sB[0], Bb, tn0, 0, 192);
  OST(sA[0], Ab, tm0, 0, 0);   OST(sA[0], Ab, tm0, 0, 64);
  OST(sB[1], Bb, tn0, 64, 0);  OST(sB[1], Bb, tn0, 64, 64);
  OST(sB[1], Bb, tn0, 64, 128);OST(sB[1], Bb, tn0, 64, 192);
  asm volatile("s_waitcnt vmcnt(4)" ::: "memory");
  OBAR;

  for (int j = 0; j < nIter; ++j) {
    const int kb = j << 7;
    const bool pf = (j + 1 < nIter);
    ORDA(0, 0); ORDB(0, 0);
    OST(sA[1], Ab, tm0, kb + 64, 0);
    OST(sA[1], Ab, tm0, kb + 64, 64);
    OBAR; OMFMAQ(0, 0); OBAR;
    ORDB(0, 1);
    OBAR; OMFMAQ(0, 1); OBAR;
    ORDA(0, 1);
    if (pf) { OST(sB[0], Bb, tn0, kb + 128, 0);
              OST(sB[0], Bb, tn0, kb + 128, 64); }
    OBAR; OMFMAQ(1, 1); OBAR;
    if (pf) { OST(sB[0], Bb, tn0, kb + 128, 128);
              OST(sB[0], Bb, tn0, kb + 128, 192); }
    OBAR; OMFMAQ(1, 0);
    if (pf) asm volatile("s_waitcnt vmcnt(4)" ::: "memory");
    else    asm volatile("s_waitcnt vmcnt(0)" ::: "memory");
    OBAR;
    ORDA(1, 0); ORDB(1, 0);
    if (pf) { OST(sA[0], Ab, tm0, kb + 128, 0);
              OST(sA[0], Ab, tm0, kb + 128, 64); }
    OBAR; OMFMAQ(0, 0); OBAR;
    ORDB(1, 1);
    OBAR; OMFMAQ(0, 1); OBAR;
    ORDA(1, 1);
    if (pf) { OST(sB[1], Bb, tn0, kb + 192, 0);
              OST(sB[1], Bb, tn0, kb + 192, 64); }
    OBAR; OMFMAQ(1, 1); OBAR;
    if (pf) { OST(sB[1], Bb, tn0, kb + 192, 128);
              OST(sB[1], Bb, tn0, kb + 192, 192); }
    OBAR; OMFMAQ(1, 0);
    asm volatile("s_waitcnt vmcnt(4)" ::: "memory");
    OBAR;
  }

#pragma unroll
  for (int mi = 0; mi < 4; ++mi) {
#pragma unroll
    for (int r = 0; r < 4; ++r) {
      const int m = tm0 + wr * 64 + mi * 16 + lq * 4 + r;
#pragma unroll
      for (int ni = 0; ni < 4; ++ni) {
        const int n = tn0 + wc * 64 + ni * 16 + lr;
        Cout[(size_t)bz * strC + (size_t)m * N + n] = acc[mi][ni][r];
      }
    }
  }
#undef OST
#undef OLDA
#undef OLDB
#undef ORDA
#undef ORDB
#undef OMFMAQ
#undef OBAR
}

extern "C" void kernel_launch(void* const* d_in, const int* in_sizes, int n_in,
                              void* d_out, int out_size, void* d_ws, size_t ws_size,
                              hipStream_t stream) {
  const float* query = (const float*)d_in[0];
  const float* key   = (const float*)d_in[1];
  const float* value = (const float*)d_in[2];
  const int*   mask  = (const int*)d_in[3];
  const float* W1    = (const float*)d_in[4];
  const float* b1    = (const float*)d_in[5];
  const float* W2    = (const float*)d_in[6];
  const float* b2    = (const float*)d_in[7];
  float* out = (float*)d_out;

  constexpr int B = 4, S = 4096, E = 512;
  constexpr long long BSE = (long long)B * S * E;
  constexpr long long SE  = (long long)S * E;
  constexpr long long SS  = (long long)S * S;
  constexpr long long BSS = (long long)B * S * S;
  constexpr long long EE  = (long long)E * E;

  char* ws = (char*)d_ws;
  unsigned short* Qb   = (unsigned short*)ws;  ws += BSE * 2;
  unsigned short* Kb   = (unsigned short*)ws;  ws += BSE * 2;
  unsigned short* Vb   = (unsigned short*)ws;  ws += BSE * 2;
  unsigned short* W1b  = (unsigned short*)ws;  ws += EE * 2;
  unsigned short* W2b  = (unsigned short*)ws;  ws += EE * 2;
  unsigned short* Kp   = (unsigned short*)ws;  ws += BSE * 2;   // [B*S, E]
  unsigned short* Vpt  = (unsigned short*)ws;  ws += BSE * 2;   // [B][E][S]
  unsigned short* alph = (unsigned short*)ws;  ws += BSS * 2;   // [B][S][S]
  unsigned int*   mbit = (unsigned int*)ws;    ws += BSS / 8;   // [B][S][S/32]

  // converts + mask packing, one launch
  prep<<<dim3(24576 + 512 + 65536), 256, 0, stream>>>(
      query, key, value, W1, W2, mask, Qb, Kb, Vb, W1b, W2b, mbit);

  // both projections, one launch (1024 blocks = 4/CU)
  proj<<<dim3(1024), 256, 0, stream>>>(Kb, W1b, Kp, b1, W2b, Vb, Vpt, b2);

  // alpha = bitmask-relu(Qb @ Kp^T), persistent over bz (grid 256 = 1/CU)
  alpha256p<<<dim3((S / 256) * (S / 256)), 512, 0, stream>>>(
      Qb, Kp, alph, mbit, S, S, E, SE, SE, SS, SS / 32);

  // out = alpha @ Vpt^T  (M=S, N=E, K=S, per batch) -- 8-phase 128x256
  outg<<<dim3((E / 256) * (S / 128) * B), 512, 0, stream>>>(
      alph, Vpt, out, S, E, S, SS, SE, SE);
}